// Round 1
// baseline (11699.612 us; speedup 1.0000x reference)
//
#include <hip/hip_runtime.h>
#include <cstdint>

#define B_  64
#define T_  1024
#define I_  256
#define H_  512

__device__ __forceinline__ uint32_t bf16_rne(float f) {
  uint32_t u = __float_as_uint(f);
  return (u + 0x7FFFu + ((u >> 16) & 1u)) >> 16;
}
__device__ __forceinline__ float bflo(uint32_t u) { return __uint_as_float(u << 16); }
__device__ __forceinline__ float bfhi(uint32_t u) { return __uint_as_float(u & 0xFFFF0000u); }

// Pack both W_hh matrices into bf16-pair stream.
// Layout per layer: [k8 (64)][j (512)][m (4)] u32, u32 m at (k8,j) = pair (k, k+1), k = 8*k8 + 2*m.
// So a uint4 load at (k8*512 + j) yields W[8k8..8k8+7][j] as 4 bf16-pairs.
__global__ void pack_whh(const float* __restrict__ W0, const float* __restrict__ W1,
                         uint32_t* __restrict__ out) {
  int idx = blockIdx.x * 256 + threadIdx.x;        // [0, 262144)
  const float* W = (idx >> 17) ? W1 : W0;
  int r  = idx & 131071;
  int k8 = r >> 11;
  int j  = (r >> 2) & 511;
  int m  = r & 3;
  int k  = k8 * 8 + m * 2;
  uint32_t lo = bf16_rne(W[k * H_ + j]);
  uint32_t hi = bf16_rne(W[(k + 1) * H_ + j]);
  out[idx] = lo | (hi << 16);
}

// Y[tile rows] = A[tile rows] @ W + bias.  Tile = 64 rows x 512 cols, block 256.
// Rows staged fully into LDS before any write -> safe for in-place (A == Y).
// NOTE: A/Y deliberately NOT __restrict__ (phase 3 calls with A == Y).
template<int K>
__global__ __launch_bounds__(256) void gemm_rows(const float* A,
    const float* __restrict__ W, const float* __restrict__ bias,
    float* Y) {
  __shared__ float As[64 * (K + 1)];               // +1 pad: a-reads 2-way (free) banks
  const int tid = threadIdx.x;
  const size_t row0 = (size_t)blockIdx.x * 64;
  const float* Ab = A + row0 * K;
  // stage 64 full rows (coalesced float4 global reads, scalar LDS writes due to pad)
  for (int idx = tid * 4; idx < 64 * K; idx += 1024) {
    float4 v = *(const float4*)(Ab + idx);
    int rr = idx / K;
    int cc = idx - rr * K;
    float* dst = &As[rr * (K + 1) + cc];
    dst[0] = v.x; dst[1] = v.y; dst[2] = v.z; dst[3] = v.w;
  }
  __syncthreads();
  const int cg = tid & 15;          // 16 col groups, cols c = cg + 16*i (interleaved, coalesced)
  const int rg = tid >> 4;          // 16 row groups x 4 rows
  float acc[4][32];
  #pragma unroll
  for (int i = 0; i < 32; ++i) {
    float bz = bias[cg + 16 * i];
    acc[0][i] = bz; acc[1][i] = bz; acc[2][i] = bz; acc[3][i] = bz;
  }
  const float* Wc = W + cg;
  for (int k = 0; k < K; ++k) {
    float a0 = As[(rg * 4 + 0) * (K + 1) + k];
    float a1 = As[(rg * 4 + 1) * (K + 1) + k];
    float a2 = As[(rg * 4 + 2) * (K + 1) + k];
    float a3 = As[(rg * 4 + 3) * (K + 1) + k];
    const float* Wk = Wc + (size_t)k * H_;
    #pragma unroll
    for (int i = 0; i < 32; ++i) {
      float w = Wk[16 * i];                        // L1-cached (shared across rg groups)
      acc[0][i] = fmaf(a0, w, acc[0][i]);
      acc[1][i] = fmaf(a1, w, acc[1][i]);
      acc[2][i] = fmaf(a2, w, acc[2][i]);
      acc[3][i] = fmaf(a3, w, acc[3][i]);
    }
  }
  float* Yb = Y + row0 * H_;
  #pragma unroll
  for (int jj = 0; jj < 4; ++jj) {
    float* Yr = Yb + (size_t)(rg * 4 + jj) * H_ + cg;
    #pragma unroll
    for (int i = 0; i < 32; ++i) Yr[16 * i] = acc[jj][i];
  }
}

// Persistent scan: one WG per batch element, thread j owns hidden unit j.
// In-place: Y holds xp on entry, h (=layer output) on exit. W streamed from L2 as bf16 pairs.
__global__ __launch_bounds__(512) void rnn_scan(float* Y,
    const uint4* __restrict__ Wp, float* __restrict__ hn) {
  __shared__ float h_lds[H_];
  const int j = threadIdx.x;
  float* Yb = Y + (size_t)blockIdx.x * (T_ * H_);
  h_lds[j] = 0.0f;
  __syncthreads();
  float v = 0.0f;
  for (int t = 0; t < T_; ++t) {
    float xp = Yb[t * H_ + j];                     // load early; consumed after k-loop
    float a0 = 0.f, a1 = 0.f, a2 = 0.f, a3 = 0.f; // 4 chains for FMA ILP
    #pragma unroll 8
    for (int i = 0; i < 64; ++i) {                 // i = k8: covers k = 8i .. 8i+7
      uint4 u = Wp[i * H_ + j];                    // coalesced 16B/lane
      float4 ha = *(const float4*)&h_lds[8 * i];   // uniform addr -> LDS broadcast
      float4 hb = *(const float4*)&h_lds[8 * i + 4];
      a0 = fmaf(bflo(u.x), ha.x, a0);
      a1 = fmaf(bfhi(u.x), ha.y, a1);
      a2 = fmaf(bflo(u.y), ha.z, a2);
      a3 = fmaf(bfhi(u.y), ha.w, a3);
      a0 = fmaf(bflo(u.z), hb.x, a0);
      a1 = fmaf(bfhi(u.z), hb.y, a1);
      a2 = fmaf(bflo(u.w), hb.z, a2);
      a3 = fmaf(bfhi(u.w), hb.w, a3);
    }
    v = tanhf(xp + ((a0 + a1) + (a2 + a3)));
    __syncthreads();                               // all h_lds reads done
    h_lds[j] = v;
    Yb[t * H_ + j] = v;                            // out[:,t,:] = h  (overwrites consumed xp)
    __syncthreads();                               // h ready for next step
  }
  hn[blockIdx.x * H_ + j] = v;                     // h_last for this batch
}

extern "C" void kernel_launch(void* const* d_in, const int* in_sizes, int n_in,
                              void* d_out, int out_size, void* d_ws, size_t ws_size,
                              hipStream_t stream) {
  const float* x     = (const float*)d_in[0];
  const float* W_ih0 = (const float*)d_in[1];
  const float* W_hh0 = (const float*)d_in[2];
  const float* b0    = (const float*)d_in[3];
  const float* W_ih1 = (const float*)d_in[4];
  const float* W_hh1 = (const float*)d_in[5];
  const float* b1    = (const float*)d_in[6];

  float* Y  = (float*)d_out;                        // [64][1024][512]
  float* hn = Y + (size_t)B_ * T_ * H_;             // [2][64][512]
  uint32_t* Wp = (uint32_t*)d_ws;                   // 262144 u32 = 1 MB (bf16-packed W_hh0|W_hh1)

  // 1. pack recurrent weights (both layers) to bf16 pairs in ws
  pack_whh<<<1024, 256, 0, stream>>>(W_hh0, W_hh1, Wp);
  // 2. Y = x @ W_ih0 + b0
  gemm_rows<I_><<<1024, 256, 0, stream>>>(x, W_ih0, b0, Y);
  // 3. scan layer 0 in-place (Y: xp0 -> out0), h_last -> hn[0]
  rnn_scan<<<B_, H_, 0, stream>>>(Y, (const uint4*)Wp, hn);
  // 4. Y = Y @ W_ih1 + b1 (in-place, row-staged)
  gemm_rows<H_><<<1024, 256, 0, stream>>>(Y, W_ih1, b1, Y);
  // 5. scan layer 1 in-place (Y: xp1 -> out1), h_last -> hn[1]
  rnn_scan<<<B_, H_, 0, stream>>>(Y, (const uint4*)(Wp + 131072), hn + B_ * H_);
}

// Round 2
// 10408.216 us; speedup vs baseline: 1.1241x; 1.1241x over previous
//
#include <hip/hip_runtime.h>
#include <cstdint>

#define B_  64
#define T_  1024
#define I_  256
#define H_  512

typedef _Float16 h2_t __attribute__((ext_vector_type(2)));

__device__ __forceinline__ uint16_t f2h(float f) {
  _Float16 h = (_Float16)f;                        // v_cvt_f16_f32, RNE
  return __builtin_bit_cast(uint16_t, h);
}

// dot2: c += a.lo*b.lo + a.hi*b.hi  (f16 x f16 -> f32 accumulate, 1 instr)
__device__ __forceinline__ float dot2f16(uint32_t a, uint32_t b, float c) {
#if __has_builtin(__builtin_amdgcn_fdot2)
  return __builtin_amdgcn_fdot2(__builtin_bit_cast(h2_t, a),
                                __builtin_bit_cast(h2_t, b), c, false);
#else
  h2_t ha = __builtin_bit_cast(h2_t, a), hb = __builtin_bit_cast(h2_t, b);
  c = fmaf((float)ha[0], (float)hb[0], c);
  c = fmaf((float)ha[1], (float)hb[1], c);
  return c;
#endif
}

// Pack both W_hh matrices into f16-pair stream.
// Layout per layer: [k8 (64)][j (512)][m (4)] u32; u32 m at (k8,j) = (W[k][j], W[k+1][j]), k = 8*k8+2m.
// A uint4 load at (k8*512 + j) yields W[8k8..8k8+7][j] as 4 f16-pairs.
__global__ void pack_whh(const float* __restrict__ W0, const float* __restrict__ W1,
                         uint32_t* __restrict__ out) {
  int idx = blockIdx.x * 256 + threadIdx.x;        // [0, 262144)
  const float* W = (idx >> 17) ? W1 : W0;
  int r  = idx & 131071;
  int k8 = r >> 11;
  int j  = (r >> 2) & 511;
  int m  = r & 3;
  int k  = k8 * 8 + m * 2;
  uint32_t lo = f2h(W[k * H_ + j]);
  uint32_t hi = f2h(W[(k + 1) * H_ + j]);
  out[idx] = lo | (hi << 16);
}

// Y[tile rows] = A[tile rows] @ W + bias.  Tile = 64 rows x 512 cols, block 256.
// Rows staged fully into LDS before any write -> safe for in-place (A == Y).
template<int K>
__global__ __launch_bounds__(256) void gemm_rows(const float* A,
    const float* __restrict__ W, const float* __restrict__ bias,
    float* Y) {
  __shared__ float As[64 * (K + 1)];
  const int tid = threadIdx.x;
  const size_t row0 = (size_t)blockIdx.x * 64;
  const float* Ab = A + row0 * K;
  for (int idx = tid * 4; idx < 64 * K; idx += 1024) {
    float4 v = *(const float4*)(Ab + idx);
    int rr = idx / K;
    int cc = idx - rr * K;
    float* dst = &As[rr * (K + 1) + cc];
    dst[0] = v.x; dst[1] = v.y; dst[2] = v.z; dst[3] = v.w;
  }
  __syncthreads();
  const int cg = tid & 15;
  const int rg = tid >> 4;
  float acc[4][32];
  #pragma unroll
  for (int i = 0; i < 32; ++i) {
    float bz = bias[cg + 16 * i];
    acc[0][i] = bz; acc[1][i] = bz; acc[2][i] = bz; acc[3][i] = bz;
  }
  const float* Wc = W + cg;
  for (int k = 0; k < K; ++k) {
    float a0 = As[(rg * 4 + 0) * (K + 1) + k];
    float a1 = As[(rg * 4 + 1) * (K + 1) + k];
    float a2 = As[(rg * 4 + 2) * (K + 1) + k];
    float a3 = As[(rg * 4 + 3) * (K + 1) + k];
    const float* Wk = Wc + (size_t)k * H_;
    #pragma unroll
    for (int i = 0; i < 32; ++i) {
      float w = Wk[16 * i];
      acc[0][i] = fmaf(a0, w, acc[0][i]);
      acc[1][i] = fmaf(a1, w, acc[1][i]);
      acc[2][i] = fmaf(a2, w, acc[2][i]);
      acc[3][i] = fmaf(a3, w, acc[3][i]);
    }
  }
  float* Yb = Y + row0 * H_;
  #pragma unroll
  for (int jj = 0; jj < 4; ++jj) {
    float* Yr = Yb + (size_t)(rg * 4 + jj) * H_ + cg;
    #pragma unroll
    for (int i = 0; i < 32; ++i) Yr[16 * i] = acc[jj][i];
  }
}

// Persistent scan: one WG per batch, thread j owns hidden unit j.
// W[k<256][j] resident in 128 VGPRs (f16 pairs); W[k>=256] streamed from L2.
// h kept in LDS as f16; dot products via v_dot2_f32_f16 (f32 accumulate).
__global__ __launch_bounds__(512) void rnn_scan(float* Y,
    const uint4* __restrict__ Wp, float* __restrict__ hn) {
  __shared__ __align__(16) _Float16 hsh[H_];
  const int j = threadIdx.x;
  float* Yb = Y + (size_t)blockIdx.x * (T_ * H_);

  // preload W rows k=0..255 for column j into registers (128 VGPRs)
  uint32_t wr[128];
  #pragma unroll
  for (int m = 0; m < 32; ++m) {
    uint4 u = Wp[m * H_ + j];
    wr[4 * m + 0] = u.x; wr[4 * m + 1] = u.y;
    wr[4 * m + 2] = u.z; wr[4 * m + 3] = u.w;
  }
  hsh[j] = (_Float16)0.0f;
  __syncthreads();
  const uint4* hq = (const uint4*)hsh;             // 64 x 16B = 512 f16 h values
  float v = 0.0f;

  for (int t = 0; t < T_; ++t) {
    float xp = Yb[t * H_ + j];
    float a0 = 0.f, a1 = 0.f, a2 = 0.f, a3 = 0.f;  // reg-W chains
    float a4 = 0.f, a5 = 0.f, a6 = 0.f, a7 = 0.f;  // streamed-W chains
    // streamed section first: global loads issue early, overlap with reg section
    #pragma unroll 8
    for (int m = 32; m < 64; ++m) {
      uint4 w = Wp[m * H_ + j];                    // L2-resident, coalesced 16B/lane
      uint4 h = hq[m];                             // uniform addr -> LDS broadcast
      a4 = dot2f16(w.x, h.x, a4);
      a5 = dot2f16(w.y, h.y, a5);
      a6 = dot2f16(w.z, h.z, a6);
      a7 = dot2f16(w.w, h.w, a7);
    }
    #pragma unroll
    for (int m = 0; m < 32; ++m) {
      uint4 h = hq[m];
      a0 = dot2f16(wr[4 * m + 0], h.x, a0);
      a1 = dot2f16(wr[4 * m + 1], h.y, a1);
      a2 = dot2f16(wr[4 * m + 2], h.z, a2);
      a3 = dot2f16(wr[4 * m + 3], h.w, a3);
    }
    float s = xp + (((a0 + a1) + (a2 + a3)) + ((a4 + a5) + (a6 + a7)));
    // tanh(s) = 1 - 2/(e^{2s}+1): ~5 instrs on the serial tail vs ~25 for tanhf
    float e = __expf(2.0f * s);
    v = fmaf(-2.0f, __builtin_amdgcn_rcpf(e + 1.0f), 1.0f);
    __syncthreads();                               // all h reads done
    hsh[j] = (_Float16)v;
    Yb[t * H_ + j] = v;                            // out[:,t,:] = h (overwrites consumed xp)
    __syncthreads();                               // h ready for next step
  }
  hn[blockIdx.x * H_ + j] = v;
}

extern "C" void kernel_launch(void* const* d_in, const int* in_sizes, int n_in,
                              void* d_out, int out_size, void* d_ws, size_t ws_size,
                              hipStream_t stream) {
  const float* x     = (const float*)d_in[0];
  const float* W_ih0 = (const float*)d_in[1];
  const float* W_hh0 = (const float*)d_in[2];
  const float* b0    = (const float*)d_in[3];
  const float* W_ih1 = (const float*)d_in[4];
  const float* W_hh1 = (const float*)d_in[5];
  const float* b1    = (const float*)d_in[6];

  float* Y  = (float*)d_out;                        // [64][1024][512]
  float* hn = Y + (size_t)B_ * T_ * H_;             // [2][64][512]
  uint32_t* Wp = (uint32_t*)d_ws;                   // 262144 u32 = 1 MB (f16-packed W_hh0|W_hh1)

  // 1. pack recurrent weights (both layers) to f16 pairs in ws
  pack_whh<<<1024, 256, 0, stream>>>(W_hh0, W_hh1, Wp);
  // 2. Y = x @ W_ih0 + b0
  gemm_rows<I_><<<1024, 256, 0, stream>>>(x, W_ih0, b0, Y);
  // 3. scan layer 0 in-place (Y: xp0 -> out0), h_last -> hn[0]
  rnn_scan<<<B_, H_, 0, stream>>>(Y, (const uint4*)Wp, hn);
  // 4. Y = Y @ W_ih1 + b1 (in-place, row-staged)
  gemm_rows<H_><<<1024, 256, 0, stream>>>(Y, W_ih1, b1, Y);
  // 5. scan layer 1 in-place (Y: xp1 -> out1), h_last -> hn[1]
  rnn_scan<<<B_, H_, 0, stream>>>(Y, (const uint4*)(Wp + 131072), hn + B_ * H_);
}

// Round 3
// 4182.696 us; speedup vs baseline: 2.7971x; 2.4884x over previous
//
#include <hip/hip_runtime.h>
#include <cstdint>

#define B_  64
#define T_  1024
#define I_  256
#define H_  512

typedef _Float16 h2_t __attribute__((ext_vector_type(2)));
typedef int sv16 __attribute__((ext_vector_type(16)));

__device__ __forceinline__ uint16_t f2h(float f) {
  _Float16 h = (_Float16)f;                        // v_cvt_f16_f32, RNE
  return __builtin_bit_cast(uint16_t, h);
}
__device__ __forceinline__ float dot2(uint32_t a, uint32_t b, float c) {
  return __builtin_amdgcn_fdot2(__builtin_bit_cast(h2_t, a),
                                __builtin_bit_cast(h2_t, b), c, false);
}
__device__ __forceinline__ float fast_tanh(float s) {
  float e = __expf(2.0f * s);
  return fmaf(-2.0f, __builtin_amdgcn_rcpf(e + 1.0f), 1.0f);
}

// select h pair P (0..63) from 4x16 SGPR vectors at compile time
template<int P>
__device__ __forceinline__ uint32_t hsel(sv16 h0, sv16 h1, sv16 h2, sv16 h3) {
  if constexpr (P < 16)      return (uint32_t)h0[P];
  else if constexpr (P < 32) return (uint32_t)h1[P - 16];
  else if constexpr (P < 48) return (uint32_t)h2[P - 32];
  else                       return (uint32_t)h3[P - 48];
}

// Pack ONE W_hh into f16-pair stream at ws[0:512KB).
// Layout: [k8 (64)][j (512)][m (4)] u32; u32 m at (k8,j) = (W[k][j],W[k+1][j]), k=8*k8+2m.
__global__ void pack_whh(const float* __restrict__ W, uint32_t* __restrict__ out) {
  int idx = blockIdx.x * 256 + threadIdx.x;        // [0, 131072)
  int k8 = idx >> 11;
  int j  = (idx >> 2) & 511;
  int m  = idx & 3;
  int k  = k8 * 8 + m * 2;
  uint32_t lo = f2h(W[k * H_ + j]);
  uint32_t hi = f2h(W[(k + 1) * H_ + j]);
  out[idx] = lo | (hi << 16);
}

// Y[tile rows] = A[tile rows] @ W + bias.  Tile = 64 rows x 512 cols, block 256.
// Rows staged fully into LDS before any write -> safe for in-place (A == Y).
template<int K>
__global__ __launch_bounds__(256) void gemm_rows(const float* A,
    const float* __restrict__ W, const float* __restrict__ bias,
    float* Y) {
  __shared__ float As[64 * (K + 1)];
  const int tid = threadIdx.x;
  const size_t row0 = (size_t)blockIdx.x * 64;
  const float* Ab = A + row0 * K;
  for (int idx = tid * 4; idx < 64 * K; idx += 1024) {
    float4 v = *(const float4*)(Ab + idx);
    int rr = idx / K;
    int cc = idx - rr * K;
    float* dst = &As[rr * (K + 1) + cc];
    dst[0] = v.x; dst[1] = v.y; dst[2] = v.z; dst[3] = v.w;
  }
  __syncthreads();
  const int cg = tid & 15;
  const int rg = tid >> 4;
  float acc[4][32];
  #pragma unroll
  for (int i = 0; i < 32; ++i) {
    float bz = bias[cg + 16 * i];
    acc[0][i] = bz; acc[1][i] = bz; acc[2][i] = bz; acc[3][i] = bz;
  }
  const float* Wc = W + cg;
  for (int k = 0; k < K; ++k) {
    float a0 = As[(rg * 4 + 0) * (K + 1) + k];
    float a1 = As[(rg * 4 + 1) * (K + 1) + k];
    float a2 = As[(rg * 4 + 2) * (K + 1) + k];
    float a3 = As[(rg * 4 + 3) * (K + 1) + k];
    const float* Wk = Wc + (size_t)k * H_;
    #pragma unroll
    for (int i = 0; i < 32; ++i) {
      float w = Wk[16 * i];
      acc[0][i] = fmaf(a0, w, acc[0][i]);
      acc[1][i] = fmaf(a1, w, acc[1][i]);
      acc[2][i] = fmaf(a2, w, acc[2][i]);
      acc[3][i] = fmaf(a3, w, acc[3][i]);
    }
  }
  float* Yb = Y + row0 * H_;
  #pragma unroll
  for (int jj = 0; jj < 4; ++jj) {
    float* Yr = Yb + (size_t)(rg * 4 + jj) * H_ + cg;
    #pragma unroll
    for (int i = 0; i < 32; ++i) Yr[16 * i] = acc[jj][i];
  }
}

// ROW: one uint4 of W (8 k = 4 pairs) against h pairs 4m..4m+3, 4 acc chains.
#define ROW(m, WEXPR) { uint4 w_ = (WEXPR); \
  a0 = dot2(w_.x, hsel<4*(m)+0>(h0,h1,h2,h3), a0); \
  a1 = dot2(w_.y, hsel<4*(m)+1>(h0,h1,h2,h3), a1); \
  a2 = dot2(w_.z, hsel<4*(m)+2>(h0,h1,h2,h3), a2); \
  a3 = dot2(w_.w, hsel<4*(m)+3>(h0,h1,h2,h3), a3); }

#define BATCH_LOAD(OFF0, OFF1, OFF2, OFF3) \
  asm volatile("s_load_dwordx16 %0, %4, " OFF0 "\n\t" \
               "s_load_dwordx16 %1, %4, " OFF1 "\n\t" \
               "s_load_dwordx16 %2, %4, " OFF2 "\n\t" \
               "s_load_dwordx16 %3, %4, " OFF3 \
               : "=s"(h0), "=s"(h1), "=s"(h2), "=s"(h3) : "s"(hbase)); \
  asm volatile("s_waitcnt lgkmcnt(0)" : "+s"(h0), "+s"(h1), "+s"(h2), "+s"(h3)); \
  __builtin_amdgcn_sched_barrier(0);

#define CONS16(W0)  ROW(0,W0(0))  ROW(1,W0(1))  ROW(2,W0(2))  ROW(3,W0(3)) \
                    ROW(4,W0(4))  ROW(5,W0(5))  ROW(6,W0(6))  ROW(7,W0(7)) \
                    ROW(8,W0(8))  ROW(9,W0(9))  ROW(10,W0(10)) ROW(11,W0(11)) \
                    ROW(12,W0(12)) ROW(13,W0(13)) ROW(14,W0(14)) ROW(15,W0(15))

#define WREG0(m) wrv[m]
#define WREG1(m) wrv[16 + (m)]
#define WLDS(m)  WL[(m) * 512 + j]
#define WSTR(m)  g[m]

// Persistent scan: one WG per batch, thread j owns hidden unit j.
// h broadcast via SGPRs: h stored to global (hb16), re-read each step with
// s_load_dwordx16 after s_dcache_inv; dot2 reads W(VGPR) x h(SGPR).
// W on-chip: k<256 in 128 VGPRs, k=256..383 in 128KB LDS, k>=384 L2-streamed.
__global__ __launch_bounds__(512, 2) void rnn_scan(float* Y,
    const uint4* __restrict__ Wp, ushort* __restrict__ hb16,
    float* __restrict__ hn) {
  __shared__ uint4 WL[16 * 512];                   // 128KB: W k8=32..47
  const int j = threadIdx.x;
  float* Yb = Y + (size_t)blockIdx.x * (T_ * H_);
  ushort* hbp = hb16 + blockIdx.x * H_;

  uint4 wrv[32];                                   // W k8=0..31 (128 VGPRs)
  #pragma unroll
  for (int m = 0; m < 32; ++m) wrv[m] = Wp[m * H_ + j];
  #pragma unroll
  for (int it = 0; it < 16; ++it) WL[it * 512 + j] = Wp[(32 + it) * 512 + j];

  // t = 0: h_prev = 0 -> h = tanh(xp)
  float xp0 = Yb[j];
  float v = fast_tanh(xp0);
  hbp[j] = f2h(v);
  Yb[j] = v;
  const uint64_t hbase = (uint64_t)(uintptr_t)hbp;
  asm volatile("s_waitcnt vmcnt(0) lgkmcnt(0)\n\ts_barrier\n\ts_dcache_inv" ::: "memory");

  for (int t = 1; t < T_; ++t) {
    float xpt = Yb[t * H_ + j];                    // consumed at tail; latency hidden
    uint4 g[16];                                   // streamed W k8=48..63
    #pragma unroll
    for (int m = 0; m < 16; ++m) g[m] = Wp[(48 + m) * H_ + j];
    float a0 = 0.f, a1 = 0.f, a2 = 0.f, a3 = 0.f;
    sv16 h0, h1, h2, h3;
    // batch 0: k 0..127 vs reg-W
    BATCH_LOAD("0x0", "0x40", "0x80", "0xc0")
    CONS16(WREG0)
    // batch 1: k 128..255 vs reg-W
    BATCH_LOAD("0x100", "0x140", "0x180", "0x1c0")
    CONS16(WREG1)
    // batch 2: k 256..383 vs LDS-W
    BATCH_LOAD("0x200", "0x240", "0x280", "0x2c0")
    CONS16(WLDS)
    // batch 3: k 384..511 vs streamed-W
    BATCH_LOAD("0x300", "0x340", "0x380", "0x3c0")
    CONS16(WSTR)

    float s = xpt + ((a0 + a1) + (a2 + a3));
    v = fast_tanh(s);
    hbp[j] = f2h(v);
    Yb[t * H_ + j] = v;
    // drain stores -> barrier -> invalidate scalar cache for next step's h
    asm volatile("s_waitcnt vmcnt(0)\n\ts_barrier\n\ts_dcache_inv" ::: "memory");
  }
  hn[blockIdx.x * H_ + j] = v;
}

extern "C" void kernel_launch(void* const* d_in, const int* in_sizes, int n_in,
                              void* d_out, int out_size, void* d_ws, size_t ws_size,
                              hipStream_t stream) {
  const float* x     = (const float*)d_in[0];
  const float* W_ih0 = (const float*)d_in[1];
  const float* W_hh0 = (const float*)d_in[2];
  const float* b0    = (const float*)d_in[3];
  const float* W_ih1 = (const float*)d_in[4];
  const float* W_hh1 = (const float*)d_in[5];
  const float* b1    = (const float*)d_in[6];

  float* Y  = (float*)d_out;                        // [64][1024][512]
  float* hn = Y + (size_t)B_ * T_ * H_;             // [2][64][512]
  uint32_t* Wp = (uint32_t*)d_ws;                   // [0,512KB): f16-packed W_hh (one layer at a time)
  ushort* hbuf = (ushort*)((char*)d_ws + 512 * 1024); // [512KB,576KB): per-block h (f16)

  // layer 0
  pack_whh<<<512, 256, 0, stream>>>(W_hh0, Wp);
  gemm_rows<I_><<<1024, 256, 0, stream>>>(x, W_ih0, b0, Y);
  rnn_scan<<<B_, H_, 0, stream>>>(Y, (const uint4*)Wp, hbuf, hn);
  // layer 1 (re-pack Wp with W_hh1 after scan0 is done with it)
  pack_whh<<<512, 256, 0, stream>>>(W_hh1, Wp);
  gemm_rows<H_><<<1024, 256, 0, stream>>>(Y, W_ih1, b1, Y);
  rnn_scan<<<B_, H_, 0, stream>>>(Y, (const uint4*)Wp, hbuf, hn + B_ * H_);
}